// Round 6
// baseline (12857.307 us; speedup 1.0000x reference)
//
#include <hip/hip_runtime.h>
#include <stdint.h>

#define SEQ   2048
#define BATCH 128
#define DIN   256
#define DH    512
#define DOUT  256

typedef uint16_t u16;
typedef uint32_t u32;
typedef __attribute__((ext_vector_type(8))) short short8;
typedef __attribute__((ext_vector_type(4))) float f32x4;

__device__ __forceinline__ u16 f2bf(float f) {
    u32 u = __float_as_uint(f);
    u += 0x7fffu + ((u >> 16) & 1u);   // RNE
    return (u16)(u >> 16);
}
__device__ __forceinline__ float bf2f(u16 h) {
    return __uint_as_float(((u32)h) << 16);
}
__device__ __forceinline__ float tanh_fast(float x) {
    float e = __expf(2.0f * x);                       // inf for large x -> rcp=0 -> 1
    return 1.0f - 2.0f * __builtin_amdgcn_rcpf(e + 1.0f);
}

// xp layout: value = xp[t][batch = bb*16 + g4*4 + r][hcol = cidx*16 + c]
// where cidx = hcol>>4 (0..31); the 4 r-values are consecutive u16.
__device__ __forceinline__ size_t xpidx(int t, int bb, int cidx, int g4, int c) {
    return (((((size_t)t * 8 + bb) * 32 + cidx) * 4 + g4) * 16 + c) * 4;
}

// ---------------------------------------------------------------------------
// Pack W_hh (fp32 [512 n][512 k]) into per-wave MFMA fragment order (bf16):
// Wp[((wv*16+kc)*8+n)*512 + lane*8 + j] =
//     W[wv*128 + n*16 + (lane&15)][kc*32 + (lane>>4)*8 + j]
// wv 0..3 (wave = 128 cols), kc 0..15, n 0..7.
// ---------------------------------------------------------------------------
__global__ void pack_whh_kernel(const float* __restrict__ W, u16* __restrict__ Wp) {
    int idx  = blockIdx.x * 256 + threadIdx.x;    // 0..32767
    int lane = idx & 63;
    int n    = (idx >> 6) & 7;
    int kc   = (idx >> 9) & 15;
    int wv   = idx >> 13;                          // 0..3
    int col = wv * 128 + n * 16 + (lane & 15);
    int k0  = kc * 32 + (lane >> 4) * 8;
    short8 v;
#pragma unroll
    for (int j = 0; j < 8; ++j) v[j] = (short)f2bf(W[(size_t)col * DH + k0 + j]);
    *reinterpret_cast<short8*>(Wp + (size_t)idx * 8) = v;
}

// ---------------------------------------------------------------------------
// Phase 1: xp = x @ W_ih^T + b_ih + b_hh, bf16, written in xpidx layout.
// M=262144, N=512, K=256.  Tile: 128(M) x 256(N), BK=64, 8 waves.
// ---------------------------------------------------------------------------
__global__ __launch_bounds__(512) void xproj_kernel(
    const float* __restrict__ x, const float* __restrict__ W_ih,
    const float* __restrict__ b_ih, const float* __restrict__ b_hh,
    u16* __restrict__ xp) {
    __shared__ u16 As[128 * 64];
    __shared__ u16 Bs[256 * 64];
    const int tid  = threadIdx.x;
    const int lane = tid & 63;
    const int wid  = tid >> 6;     // 0..7
    const int wm   = wid >> 2;     // 0..1
    const int wn   = wid & 3;      // 0..3
    const int mt   = blockIdx.x;   // 0..2047
    const int nt   = blockIdx.y;   // 0..1

    f32x4 acc[4][4];
#pragma unroll
    for (int i = 0; i < 4; ++i)
#pragma unroll
        for (int j = 0; j < 4; ++j) acc[i][j] = (f32x4){0.f, 0.f, 0.f, 0.f};

    for (int kk = 0; kk < DIN; kk += 64) {
        __syncthreads();
        {   // stage A: 128 rows x 64 k (fp32 -> bf16), 16 elems/thread
            int r = tid >> 2, q = tid & 3;
            const float4* gp = (const float4*)(x + (size_t)(mt * 128 + r) * DIN + kk + q * 16);
            float4 v0 = gp[0], v1 = gp[1], v2 = gp[2], v3 = gp[3];
            short8 h0, h1;
            h0[0]=(short)f2bf(v0.x); h0[1]=(short)f2bf(v0.y); h0[2]=(short)f2bf(v0.z); h0[3]=(short)f2bf(v0.w);
            h0[4]=(short)f2bf(v1.x); h0[5]=(short)f2bf(v1.y); h0[6]=(short)f2bf(v1.z); h0[7]=(short)f2bf(v1.w);
            h1[0]=(short)f2bf(v2.x); h1[1]=(short)f2bf(v2.y); h1[2]=(short)f2bf(v2.z); h1[3]=(short)f2bf(v2.w);
            h1[4]=(short)f2bf(v3.x); h1[5]=(short)f2bf(v3.y); h1[6]=(short)f2bf(v3.z); h1[7]=(short)f2bf(v3.w);
            int base = r * 64, sw = (r & 7) << 3, ke = q * 16;
            *(short8*)&As[base + (ke ^ sw)]       = h0;
            *(short8*)&As[base + ((ke + 8) ^ sw)] = h1;
        }
        {   // stage B: 256 rows x 64 k, 32 elems/thread
            int r = tid >> 1, hf = tid & 1;
            const float4* gp = (const float4*)(W_ih + (size_t)(nt * 256 + r) * DIN + kk + hf * 32);
            int base = r * 64, sw = (r & 7) << 3;
#pragma unroll
            for (int cp = 0; cp < 2; ++cp) {
                float4 u0 = gp[cp*4+0], u1 = gp[cp*4+1], u2 = gp[cp*4+2], u3 = gp[cp*4+3];
                short8 t0, t1;
                t0[0]=(short)f2bf(u0.x); t0[1]=(short)f2bf(u0.y); t0[2]=(short)f2bf(u0.z); t0[3]=(short)f2bf(u0.w);
                t0[4]=(short)f2bf(u1.x); t0[5]=(short)f2bf(u1.y); t0[6]=(short)f2bf(u1.z); t0[7]=(short)f2bf(u1.w);
                t1[0]=(short)f2bf(u2.x); t1[1]=(short)f2bf(u2.y); t1[2]=(short)f2bf(u2.z); t1[3]=(short)f2bf(u2.w);
                t1[4]=(short)f2bf(u3.x); t1[5]=(short)f2bf(u3.y); t1[6]=(short)f2bf(u3.z); t1[7]=(short)f2bf(u3.w);
                int ke = hf * 32 + cp * 16;
                *(short8*)&Bs[base + (ke ^ sw)]       = t0;
                *(short8*)&Bs[base + ((ke + 8) ^ sw)] = t1;
            }
        }
        __syncthreads();
#pragma unroll
        for (int kt = 0; kt < 2; ++kt) {
            short8 a[4], b[4];
            int ke = kt * 32 + (lane >> 4) * 8;
#pragma unroll
            for (int mi = 0; mi < 4; ++mi) {
                int rr = wm * 64 + mi * 16 + (lane & 15);
                a[mi] = *(const short8*)&As[rr * 64 + (ke ^ ((rr & 7) << 3))];
            }
#pragma unroll
            for (int ni = 0; ni < 4; ++ni) {
                int rr = wn * 64 + ni * 16 + (lane & 15);
                b[ni] = *(const short8*)&Bs[rr * 64 + (ke ^ ((rr & 7) << 3))];
            }
#pragma unroll
            for (int mi = 0; mi < 4; ++mi)
#pragma unroll
                for (int ni = 0; ni < 4; ++ni)
                    acc[mi][ni] = __builtin_amdgcn_mfma_f32_16x16x32_bf16(a[mi], b[ni], acc[mi][ni], 0, 0, 0);
        }
    }
    // epilogue -> xpidx layout. t = mt, bb = wm*4+mi, cidx = (nt*4+wn)*4+ni.
    int g4 = lane >> 4, c = lane & 15;
#pragma unroll
    for (int ni = 0; ni < 4; ++ni) {
        int col = nt * 256 + wn * 64 + ni * 16 + c;
        float bias = b_ih[col] + b_hh[col];
#pragma unroll
        for (int mi = 0; mi < 4; ++mi) {
            u32 lo = (u32)f2bf(acc[mi][ni][0] + bias) | ((u32)f2bf(acc[mi][ni][1] + bias) << 16);
            u32 hi = (u32)f2bf(acc[mi][ni][2] + bias) | ((u32)f2bf(acc[mi][ni][3] + bias) << 16);
            uint2 v; v.x = lo; v.y = hi;
            *reinterpret_cast<uint2*>(xp + xpidx(mt, wm * 4 + mi, (nt * 4 + wn) * 4 + ni, g4, c)) = v;
        }
    }
}

// ---------------------------------------------------------------------------
// Phase 2: recurrence. 8 blocks x 256 thr (4 waves), 1 block/CU, 1 wave/SIMD.
// __launch_bounds__(256, 1) -> 512-reg/wave budget (gfx950 unified VGPR/AGPR).
// Rounds 2-5 lesson: at a 256-reg budget the allocator MUST kill W live
// ranges (remat/shuttle) — feasibility, not pins, is what keeps W resident.
// Wave wv owns H-cols [128wv, 128wv+128), 8 n-frags. W_hh split:
//   kc 0..8  -> registers (72 frags = 288 regs; demand ~460 < 512, no pins)
//   kc 9..11 -> LDS (96 KB, DS pipe)
//   kc 12..15 -> streamed from L2 each step (128 KB/CU, VMEM pipe; stream
//               pointer re-defined per-iter by empty asm so LICM can't hoist
//               128 regs of loads — this pin was correctness-proven in r3)
// h double-buffered in 32 KB LDS (total 128 KB). acc initialized from xp.
// All MFMAs are intrinsics (compiler owns all hazards).
// ---------------------------------------------------------------------------
__global__ __launch_bounds__(256, 1) void rnn_rec_kernel(
    const u16* __restrict__ xp, const u16* __restrict__ Wp,
    u16* __restrict__ h_last) {
    __shared__ u16 W_lds[4 * 3 * 8 * 512];   // 96 KB : kc 9..11
    __shared__ u16 h_s[2][16 * 512];         // 32 KB
    const int tid = threadIdx.x, lane = tid & 63, wv = tid >> 6;  // wv 0..3
    const int bb = blockIdx.x;
    const int g4 = lane >> 4, c = lane & 15;
    const int arow = lane & 15;
    const int asw = (arow & 7) << 3;

    // stage W kc=9..11 into LDS (each wave its own 24 KB slice)
#pragma unroll
    for (int f = 0; f < 24; ++f) {           // f = q*8 + n, q = kc-9
        int q = f >> 3, n = f & 7;
        short8 v = *(const short8*)(Wp + ((size_t)((wv * 16 + 9 + q) * 8 + n)) * 512 + lane * 8);
        *(short8*)&W_lds[((wv * 3 + q) * 8 + n) * 512 + lane * 8] = v;
    }
    // W kc=0..8 into registers (72 x short8 = 288 regs). No pins: budget 512,
    // demand ~460 -> allocator has no reason to rematerialize.
    short8 wr[9][8];
#pragma unroll
    for (int kc = 0; kc < 9; ++kc)
#pragma unroll
        for (int n = 0; n < 8; ++n)
            wr[kc][n] = *(const short8*)(Wp + ((size_t)((wv * 16 + kc) * 8 + n)) * 512 + lane * 8);

    // h(0) = 0
#pragma unroll
    for (int i = 0; i < 4; ++i)
        *(short8*)&h_s[0][tid * 32 + i * 8] = (short8)0;

    // prefetch xp(0): cidx = wv*8 + n
    uint2 xn[8];
#pragma unroll
    for (int n = 0; n < 8; ++n)
        xn[n] = *(const uint2*)(xp + xpidx(0, bb, wv * 8 + n, g4, c));

    const u16* wps_base = Wp + ((size_t)((wv * 16 + 12) * 8)) * 512 + lane * 8;

    __syncthreads();

    for (int t = 0; t < SEQ; ++t) {
        const int cur = t & 1, nxt = cur ^ 1;

        // break loop-invariance of the streamed-W address each iteration
        const u16* wps = wps_base;
        asm volatile("" : "+v"(wps));

        // acc initialized from xp(t) (held in xn) — VALU; intrinsics follow,
        // so the compiler owns the VALU->MFMA hazard.
        f32x4 acc[8];
#pragma unroll
        for (int n = 0; n < 8; ++n) {
            acc[n][0] = __uint_as_float(xn[n].x << 16);
            acc[n][1] = __uint_as_float(xn[n].x & 0xffff0000u);
            acc[n][2] = __uint_as_float(xn[n].y << 16);
            acc[n][3] = __uint_as_float(xn[n].y & 0xffff0000u);
        }
        // prefetch xp(t+1)
        if (t + 1 < SEQ) {
#pragma unroll
            for (int n = 0; n < 8; ++n)
                xn[n] = *(const uint2*)(xp + xpidx(t + 1, bb, wv * 8 + n, g4, c));
        }

        // kc 0..8 : B from registers
#pragma unroll
        for (int kc = 0; kc < 9; ++kc) {
            short8 a = *(const short8*)&h_s[cur][arow * 512 + ((kc * 32 + g4 * 8) ^ asw)];
#pragma unroll
            for (int n = 0; n < 8; ++n)
                acc[n] = __builtin_amdgcn_mfma_f32_16x16x32_bf16(a, wr[kc][n], acc[n], 0, 0, 0);
        }
        // kc 9..11 : B from LDS
#pragma unroll
        for (int q = 0; q < 3; ++q) {
            int kc = 9 + q;
            short8 a = *(const short8*)&h_s[cur][arow * 512 + ((kc * 32 + g4 * 8) ^ asw)];
#pragma unroll
            for (int n = 0; n < 8; ++n) {
                short8 b = *(const short8*)&W_lds[((wv * 3 + q) * 8 + n) * 512 + lane * 8];
                acc[n] = __builtin_amdgcn_mfma_f32_16x16x32_bf16(a, b, acc[n], 0, 0, 0);
            }
        }
        // kc 12..15 : B streamed from L2 (VMEM pipe)
#pragma unroll
        for (int s = 0; s < 4; ++s) {
            int kc = 12 + s;
            short8 a = *(const short8*)&h_s[cur][arow * 512 + ((kc * 32 + g4 * 8) ^ asw)];
#pragma unroll
            for (int n = 0; n < 8; ++n) {
                short8 b = *(const short8*)(wps + (size_t)(s * 8 + n) * 512);
                acc[n] = __builtin_amdgcn_mfma_f32_16x16x32_bf16(a, b, acc[n], 0, 0, 0);
            }
        }

        // epilogue: acc row r -> batch row 4*g4+r, col = wv*128 + n*16 + c
#pragma unroll
        for (int n = 0; n < 8; ++n) {
            int colL = wv * 128 + n * 16 + c;
#pragma unroll
            for (int r = 0; r < 4; ++r) {
                int row = 4 * g4 + r;
                h_s[nxt][row * 512 + (colL ^ ((row & 7) << 3))] = f2bf(tanh_fast(acc[n][r]));
            }
        }
        __syncthreads();
    }
    {   // final h is in h_s[0] (SEQ even). Un-swizzle and store 32 u16/thread.
        int i = tid * 32;
        int row = i >> 9, colb = i & 511;
        int sw = (row & 7) << 3;
#pragma unroll
        for (int j = 0; j < 4; ++j) {
            short8 v = *(const short8*)&h_s[0][row * 512 + ((colb + j * 8) ^ sw)];
            *(short8*)(h_last + (size_t)(bb * 16 + row) * DH + colb + j * 8) = v;
        }
    }
}

// ---------------------------------------------------------------------------
// Phase 3: out[b][o] = h_last[b,:]·W_fc[o,:] + b_fc[o]   (fp32 VALU, tiny)
// ---------------------------------------------------------------------------
__global__ __launch_bounds__(256) void fc_kernel(
    const u16* __restrict__ h_last, const float* __restrict__ W_fc,
    const float* __restrict__ b_fc, float* __restrict__ out) {
    __shared__ float hsh[DH];
    int b = blockIdx.x, o = threadIdx.x;
    for (int i = threadIdx.x; i < DH; i += 256) hsh[i] = bf2f(h_last[(size_t)b * DH + i]);
    __syncthreads();
    const float* w = W_fc + (size_t)o * DH;
    float s = 0.f;
#pragma unroll 8
    for (int k = 0; k < DH; ++k) s += hsh[k] * w[k];
    out[(size_t)b * DOUT + o] = s + b_fc[o];
}

extern "C" void kernel_launch(void* const* d_in, const int* in_sizes, int n_in,
                              void* d_out, int out_size, void* d_ws, size_t ws_size,
                              hipStream_t stream) {
    const float* x    = (const float*)d_in[0];
    const float* W_ih = (const float*)d_in[1];
    const float* W_hh = (const float*)d_in[2];
    const float* b_ih = (const float*)d_in[3];
    const float* b_hh = (const float*)d_in[4];
    const float* W_fc = (const float*)d_in[5];
    const float* b_fc = (const float*)d_in[6];
    float* out = (float*)d_out;

    u16* xp     = (u16*)d_ws;                               // 2048*128*512 bf16 = 256 MB
    u16* Wp     = xp + (size_t)SEQ * BATCH * DH;            // 512 KB
    u16* h_last = Wp + (size_t)4 * 16 * 8 * 512;            // 128 KB

    hipLaunchKernelGGL(pack_whh_kernel, dim3(128), dim3(256), 0, stream, W_hh, Wp);
    hipLaunchKernelGGL(xproj_kernel, dim3(2048, 2), dim3(512), 0, stream, x, W_ih, b_ih, b_hh, xp);
    hipLaunchKernelGGL(rnn_rec_kernel, dim3(8), dim3(256), 0, stream, xp, Wp, h_last);
    hipLaunchKernelGGL(fc_kernel, dim3(128), dim3(256), 0, stream, h_last, W_fc, b_fc, out);
}

// Round 7
// 6170.559 us; speedup vs baseline: 2.0837x; 2.0837x over previous
//
#include <hip/hip_runtime.h>
#include <stdint.h>

#define SEQ   2048
#define BATCH 128
#define DIN   256
#define DH    512
#define DOUT  256

typedef uint16_t u16;
typedef uint32_t u32;
typedef __attribute__((ext_vector_type(8))) short short8;
typedef __attribute__((ext_vector_type(4))) float f32x4;

__device__ __forceinline__ u16 f2bf(float f) {
    u32 u = __float_as_uint(f);
    u += 0x7fffu + ((u >> 16) & 1u);   // RNE
    return (u16)(u >> 16);
}
__device__ __forceinline__ float bf2f(u16 h) {
    return __uint_as_float(((u32)h) << 16);
}
__device__ __forceinline__ float tanh_fast(float x) {
    float e = __expf(2.0f * x);                       // inf for large x -> rcp=0 -> 1
    return 1.0f - 2.0f * __builtin_amdgcn_rcpf(e + 1.0f);
}

// xp layout: XPIDX(t, bblk, wv, n, g4, c) + r  (u16 units)
// value = xp[t][batch = bblk*16 + g4*4 + r][hcol = wv*64 + n*16 + c]
__device__ __forceinline__ size_t xpidx(int t, int bb, int wv, int n, int g4, int c) {
    return ((((((size_t)t * 8 + bb) * 8 + wv) * 4 + n) * 4 + g4) * 16 + c) * 4;
}

// ---------------------------------------------------------------------------
// Pack W_hh (fp32 [512 n][512 k]) into per-wave MFMA fragment order (bf16):
// Wp[((wv*16+kc)*4+n)*512 + lane*8 + j] =
//     W[wv*64 + n*16 + (lane&15)][kc*32 + (lane>>4)*8 + j]
// wv 0..7 (wave = 64 cols), kc 0..15, n 0..3.
// ---------------------------------------------------------------------------
__global__ void pack_whh_kernel(const float* __restrict__ W, u16* __restrict__ Wp) {
    int idx  = blockIdx.x * 256 + threadIdx.x;    // 0..32767
    int lane = idx & 63;
    int n    = (idx >> 6) & 3;
    int kc   = (idx >> 8) & 15;
    int wv   = idx >> 12;                          // 0..7
    int col = wv * 64 + n * 16 + (lane & 15);
    int k0  = kc * 32 + (lane >> 4) * 8;
    short8 v;
#pragma unroll
    for (int j = 0; j < 8; ++j) v[j] = (short)f2bf(W[(size_t)col * DH + k0 + j]);
    *reinterpret_cast<short8*>(Wp + (size_t)idx * 8) = v;
}

// ---------------------------------------------------------------------------
// Phase 1: xp = x @ W_ih^T + b_ih + b_hh, bf16, written in xpidx layout.
// M=262144, N=512, K=256.  Tile: 128(M) x 256(N), BK=64, 8 waves.
// ---------------------------------------------------------------------------
__global__ __launch_bounds__(512) void xproj_kernel(
    const float* __restrict__ x, const float* __restrict__ W_ih,
    const float* __restrict__ b_ih, const float* __restrict__ b_hh,
    u16* __restrict__ xp) {
    __shared__ u16 As[128 * 64];
    __shared__ u16 Bs[256 * 64];
    const int tid  = threadIdx.x;
    const int lane = tid & 63;
    const int wid  = tid >> 6;     // 0..7
    const int wm   = wid >> 2;     // 0..1
    const int wn   = wid & 3;      // 0..3
    const int mt   = blockIdx.x;   // 0..2047
    const int nt   = blockIdx.y;   // 0..1

    f32x4 acc[4][4];
#pragma unroll
    for (int i = 0; i < 4; ++i)
#pragma unroll
        for (int j = 0; j < 4; ++j) acc[i][j] = (f32x4){0.f, 0.f, 0.f, 0.f};

    for (int kk = 0; kk < DIN; kk += 64) {
        __syncthreads();
        {   // stage A: 128 rows x 64 k (fp32 -> bf16), 16 elems/thread
            int r = tid >> 2, q = tid & 3;
            const float4* gp = (const float4*)(x + (size_t)(mt * 128 + r) * DIN + kk + q * 16);
            float4 v0 = gp[0], v1 = gp[1], v2 = gp[2], v3 = gp[3];
            short8 h0, h1;
            h0[0]=(short)f2bf(v0.x); h0[1]=(short)f2bf(v0.y); h0[2]=(short)f2bf(v0.z); h0[3]=(short)f2bf(v0.w);
            h0[4]=(short)f2bf(v1.x); h0[5]=(short)f2bf(v1.y); h0[6]=(short)f2bf(v1.z); h0[7]=(short)f2bf(v1.w);
            h1[0]=(short)f2bf(v2.x); h1[1]=(short)f2bf(v2.y); h1[2]=(short)f2bf(v2.z); h1[3]=(short)f2bf(v2.w);
            h1[4]=(short)f2bf(v3.x); h1[5]=(short)f2bf(v3.y); h1[6]=(short)f2bf(v3.z); h1[7]=(short)f2bf(v3.w);
            int base = r * 64, sw = (r & 7) << 3, ke = q * 16;
            *(short8*)&As[base + (ke ^ sw)]       = h0;
            *(short8*)&As[base + ((ke + 8) ^ sw)] = h1;
        }
        {   // stage B: 256 rows x 64 k, 32 elems/thread
            int r = tid >> 1, hf = tid & 1;
            const float4* gp = (const float4*)(W_ih + (size_t)(nt * 256 + r) * DIN + kk + hf * 32);
            int base = r * 64, sw = (r & 7) << 3;
#pragma unroll
            for (int cp = 0; cp < 2; ++cp) {
                float4 u0 = gp[cp*4+0], u1 = gp[cp*4+1], u2 = gp[cp*4+2], u3 = gp[cp*4+3];
                short8 t0, t1;
                t0[0]=(short)f2bf(u0.x); t0[1]=(short)f2bf(u0.y); t0[2]=(short)f2bf(u0.z); t0[3]=(short)f2bf(u0.w);
                t0[4]=(short)f2bf(u1.x); t0[5]=(short)f2bf(u1.y); t0[6]=(short)f2bf(u1.z); t0[7]=(short)f2bf(u1.w);
                t1[0]=(short)f2bf(u2.x); t1[1]=(short)f2bf(u2.y); t1[2]=(short)f2bf(u2.z); t1[3]=(short)f2bf(u2.w);
                t1[4]=(short)f2bf(u3.x); t1[5]=(short)f2bf(u3.y); t1[6]=(short)f2bf(u3.z); t1[7]=(short)f2bf(u3.w);
                int ke = hf * 32 + cp * 16;
                *(short8*)&Bs[base + (ke ^ sw)]       = t0;
                *(short8*)&Bs[base + ((ke + 8) ^ sw)] = t1;
            }
        }
        __syncthreads();
#pragma unroll
        for (int kt = 0; kt < 2; ++kt) {
            short8 a[4], b[4];
            int ke = kt * 32 + (lane >> 4) * 8;
#pragma unroll
            for (int mi = 0; mi < 4; ++mi) {
                int rr = wm * 64 + mi * 16 + (lane & 15);
                a[mi] = *(const short8*)&As[rr * 64 + (ke ^ ((rr & 7) << 3))];
            }
#pragma unroll
            for (int ni = 0; ni < 4; ++ni) {
                int rr = wn * 64 + ni * 16 + (lane & 15);
                b[ni] = *(const short8*)&Bs[rr * 64 + (ke ^ ((rr & 7) << 3))];
            }
#pragma unroll
            for (int mi = 0; mi < 4; ++mi)
#pragma unroll
                for (int ni = 0; ni < 4; ++ni)
                    acc[mi][ni] = __builtin_amdgcn_mfma_f32_16x16x32_bf16(a[mi], b[ni], acc[mi][ni], 0, 0, 0);
        }
    }
    // epilogue -> xpidx layout. t = mt, bblk = wm*4+mi, wv = nt*4+wn, n = ni.
    int g4 = lane >> 4, c = lane & 15;
#pragma unroll
    for (int ni = 0; ni < 4; ++ni) {
        int col = nt * 256 + wn * 64 + ni * 16 + c;
        float bias = b_ih[col] + b_hh[col];
#pragma unroll
        for (int mi = 0; mi < 4; ++mi) {
            u32 lo = (u32)f2bf(acc[mi][ni][0] + bias) | ((u32)f2bf(acc[mi][ni][1] + bias) << 16);
            u32 hi = (u32)f2bf(acc[mi][ni][2] + bias) | ((u32)f2bf(acc[mi][ni][3] + bias) << 16);
            uint2 v; v.x = lo; v.y = hi;
            *reinterpret_cast<uint2*>(xp + xpidx(mt, wm * 4 + mi, nt * 4 + wn, ni, g4, c)) = v;
        }
    }
}

// ---------------------------------------------------------------------------
// Phase 2: recurrence. 8 blocks x 512 thr (8 waves, 2/SIMD), 1 block/CU.
// Wave wv owns H-cols [64wv, 64wv+64), 4 n-frags. W_hh split (FEASIBLE
// register demand — the rounds-2..6 lesson: arch-VGPR cap is 256/wave, so
// W-in-regs + working set must stay under 256 or the allocator kills ALL
// W live ranges and re-streams 416 KB/step from L2):
//   kc 0..9   -> registers (40 frags = 160 regs; total demand ~235 < 256)
//   kc 10..12 -> LDS (96 KB, DS pipe)
//   kc 13..15 -> streamed from L2 each step (96 KB/CU, VMEM pipe; stream
//                pointer re-defined per-iter by empty asm so LICM can't
//                hoist 48 regs of loads — correctness-proven in r3)
// h double-buffered in 32 KB LDS (total 128 KB). acc initialized from xp.
// All MFMAs are intrinsics (compiler owns all hazards — r4/r5 lesson).
// ---------------------------------------------------------------------------
__global__ __launch_bounds__(512, 2) void rnn_rec_kernel(
    const u16* __restrict__ xp, const u16* __restrict__ Wp,
    u16* __restrict__ h_last) {
    __shared__ u16 W_lds[8 * 3 * 4 * 512];   // 96 KB : kc 10..12
    __shared__ u16 h_s[2][16 * 512];         // 32 KB
    const int tid = threadIdx.x, lane = tid & 63, wv = tid >> 6;  // wv 0..7
    const int bb = blockIdx.x;
    const int g4 = lane >> 4, c = lane & 15;
    const int arow = lane & 15;
    const int asw = (arow & 7) << 3;

    // stage W kc=10..12 into LDS (each wave its own 12 KB slice)
#pragma unroll
    for (int f = 0; f < 12; ++f) {           // f = q*4 + n, q = kc-10
        int q = f >> 2, n = f & 3;
        short8 v = *(const short8*)(Wp + ((size_t)((wv * 16 + 10 + q) * 4 + n)) * 512 + lane * 8);
        *(short8*)&W_lds[((wv * 3 + q) * 4 + n) * 512 + lane * 8] = v;
    }
    // W kc=0..9 into registers (40 x short8 = 160 regs). No pins: demand is
    // feasible (~235 of 256), so the allocator has no reason to remat.
    short8 wr[10][4];
#pragma unroll
    for (int kc = 0; kc < 10; ++kc)
#pragma unroll
        for (int n = 0; n < 4; ++n)
            wr[kc][n] = *(const short8*)(Wp + ((size_t)((wv * 16 + kc) * 4 + n)) * 512 + lane * 8);

    // h(0) = 0
    *(short8*)&h_s[0][tid * 16]     = (short8)0;
    *(short8*)&h_s[0][tid * 16 + 8] = (short8)0;

    // prefetch xp(0)
    uint2 xn[4];
#pragma unroll
    for (int n = 0; n < 4; ++n)
        xn[n] = *(const uint2*)(xp + xpidx(0, bb, wv, n, g4, c));

    const u16* wps_base = Wp + ((size_t)(wv * 16 + 13) * 4) * 512 + lane * 8;

    __syncthreads();

    for (int t = 0; t < SEQ; ++t) {
        const int cur = t & 1, nxt = cur ^ 1;

        // break loop-invariance of the streamed-W address each iteration
        const u16* wps = wps_base;
        asm volatile("" : "+v"(wps));

        // acc initialized from xp(t) (held in xn) — VALU; intrinsic MFMAs
        // follow, so the compiler owns the VALU->MFMA hazard.
        f32x4 acc[4];
#pragma unroll
        for (int n = 0; n < 4; ++n) {
            acc[n][0] = __uint_as_float(xn[n].x << 16);
            acc[n][1] = __uint_as_float(xn[n].x & 0xffff0000u);
            acc[n][2] = __uint_as_float(xn[n].y << 16);
            acc[n][3] = __uint_as_float(xn[n].y & 0xffff0000u);
        }
        // prefetch xp(t+1)
        if (t + 1 < SEQ) {
#pragma unroll
            for (int n = 0; n < 4; ++n)
                xn[n] = *(const uint2*)(xp + xpidx(t + 1, bb, wv, n, g4, c));
        }

        // kc 0..9 : B from registers
#pragma unroll
        for (int kc = 0; kc < 10; ++kc) {
            short8 a = *(const short8*)&h_s[cur][arow * 512 + ((kc * 32 + g4 * 8) ^ asw)];
#pragma unroll
            for (int n = 0; n < 4; ++n)
                acc[n] = __builtin_amdgcn_mfma_f32_16x16x32_bf16(a, wr[kc][n], acc[n], 0, 0, 0);
        }
        // kc 10..12 : B from LDS (DS pipe)
#pragma unroll
        for (int q = 0; q < 3; ++q) {
            int kc = 10 + q;
            short8 a = *(const short8*)&h_s[cur][arow * 512 + ((kc * 32 + g4 * 8) ^ asw)];
#pragma unroll
            for (int n = 0; n < 4; ++n) {
                short8 b = *(const short8*)&W_lds[((wv * 3 + q) * 4 + n) * 512 + lane * 8];
                acc[n] = __builtin_amdgcn_mfma_f32_16x16x32_bf16(a, b, acc[n], 0, 0, 0);
            }
        }
        // kc 13..15 : B streamed from L2 (VMEM pipe)
#pragma unroll
        for (int s = 0; s < 3; ++s) {
            int kc = 13 + s;
            short8 a = *(const short8*)&h_s[cur][arow * 512 + ((kc * 32 + g4 * 8) ^ asw)];
#pragma unroll
            for (int n = 0; n < 4; ++n) {
                short8 b = *(const short8*)(wps + (size_t)(s * 4 + n) * 512);
                acc[n] = __builtin_amdgcn_mfma_f32_16x16x32_bf16(a, b, acc[n], 0, 0, 0);
            }
        }

        // epilogue: acc row r -> batch row 4*g4+r, col = wv*64 + n*16 + c
#pragma unroll
        for (int n = 0; n < 4; ++n) {
            int colL = wv * 64 + n * 16 + c;
#pragma unroll
            for (int r = 0; r < 4; ++r) {
                int row = 4 * g4 + r;
                h_s[nxt][row * 512 + (colL ^ ((row & 7) << 3))] = f2bf(tanh_fast(acc[n][r]));
            }
        }
        __syncthreads();
    }
    {   // final h is in h_s[0] (SEQ even). Un-swizzle and store 16 u16/thread.
        int i = tid * 16;
        int row = i >> 9, colb = i & 511;
        int sw = (row & 7) << 3;
        short8 v0 = *(const short8*)&h_s[0][row * 512 + (colb ^ sw)];
        short8 v1 = *(const short8*)&h_s[0][row * 512 + ((colb + 8) ^ sw)];
        *(short8*)(h_last + (size_t)(bb * 16 + row) * DH + colb)     = v0;
        *(short8*)(h_last + (size_t)(bb * 16 + row) * DH + colb + 8) = v1;
    }
}

// ---------------------------------------------------------------------------
// Phase 3: out[b][o] = h_last[b,:]·W_fc[o,:] + b_fc[o]   (fp32 VALU, tiny)
// ---------------------------------------------------------------------------
__global__ __launch_bounds__(256) void fc_kernel(
    const u16* __restrict__ h_last, const float* __restrict__ W_fc,
    const float* __restrict__ b_fc, float* __restrict__ out) {
    __shared__ float hsh[DH];
    int b = blockIdx.x, o = threadIdx.x;
    for (int i = threadIdx.x; i < DH; i += 256) hsh[i] = bf2f(h_last[(size_t)b * DH + i]);
    __syncthreads();
    const float* w = W_fc + (size_t)o * DH;
    float s = 0.f;
#pragma unroll 8
    for (int k = 0; k < DH; ++k) s += hsh[k] * w[k];
    out[(size_t)b * DOUT + o] = s + b_fc[o];
}

extern "C" void kernel_launch(void* const* d_in, const int* in_sizes, int n_in,
                              void* d_out, int out_size, void* d_ws, size_t ws_size,
                              hipStream_t stream) {
    const float* x    = (const float*)d_in[0];
    const float* W_ih = (const float*)d_in[1];
    const float* W_hh = (const float*)d_in[2];
    const float* b_ih = (const float*)d_in[3];
    const float* b_hh = (const float*)d_in[4];
    const float* W_fc = (const float*)d_in[5];
    const float* b_fc = (const float*)d_in[6];
    float* out = (float*)d_out;

    u16* xp     = (u16*)d_ws;                               // 2048*128*512 bf16 = 256 MB
    u16* Wp     = xp + (size_t)SEQ * BATCH * DH;            // 512 KB
    u16* h_last = Wp + (size_t)8 * 16 * 4 * 512;            // 128 KB

    hipLaunchKernelGGL(pack_whh_kernel, dim3(128), dim3(256), 0, stream, W_hh, Wp);
    hipLaunchKernelGGL(xproj_kernel, dim3(2048, 2), dim3(512), 0, stream, x, W_ih, b_ih, b_hh, xp);
    hipLaunchKernelGGL(rnn_rec_kernel, dim3(8), dim3(512), 0, stream, xp, Wp, h_last);
    hipLaunchKernelGGL(fc_kernel, dim3(128), dim3(256), 0, stream, h_last, W_fc, b_fc, out);
}

// Round 8
// 6157.502 us; speedup vs baseline: 2.0881x; 1.0021x over previous
//
#include <hip/hip_runtime.h>
#include <stdint.h>

#define SEQ   2048
#define BATCH 128
#define DIN   256
#define DH    512
#define DOUT  256

typedef uint16_t u16;
typedef uint32_t u32;
typedef __attribute__((ext_vector_type(8))) short short8;
typedef __attribute__((ext_vector_type(4))) float f32x4;

__device__ __forceinline__ u16 f2bf(float f) {
    u32 u = __float_as_uint(f);
    u += 0x7fffu + ((u >> 16) & 1u);   // RNE
    return (u16)(u >> 16);
}
__device__ __forceinline__ float bf2f(u16 h) {
    return __uint_as_float(((u32)h) << 16);
}
__device__ __forceinline__ float tanh_fast(float x) {
    float e = __expf(2.0f * x);                       // inf for large x -> rcp=0 -> 1
    return 1.0f - 2.0f * __builtin_amdgcn_rcpf(e + 1.0f);
}

// xp layout: XPIDX(t, bblk, wv, n, g4, c) + r  (u16 units)
// value = xp[t][batch = bblk*16 + g4*4 + r][hcol = wv*64 + n*16 + c]
__device__ __forceinline__ size_t xpidx(int t, int bb, int wv, int n, int g4, int c) {
    return ((((((size_t)t * 8 + bb) * 8 + wv) * 4 + n) * 4 + g4) * 16 + c) * 4;
}

// ---------------------------------------------------------------------------
// Pack W_hh (fp32 [512 n][512 k]) into per-wave MFMA fragment order (bf16):
// Wp[((wv*16+kc)*4+n)*512 + lane*8 + j] =
//     W[wv*64 + n*16 + (lane&15)][kc*32 + (lane>>4)*8 + j]
// wv 0..7 (wave = 64 cols), kc 0..15, n 0..3.
// ---------------------------------------------------------------------------
__global__ void pack_whh_kernel(const float* __restrict__ W, u16* __restrict__ Wp) {
    int idx  = blockIdx.x * 256 + threadIdx.x;    // 0..32767
    int lane = idx & 63;
    int n    = (idx >> 6) & 3;
    int kc   = (idx >> 8) & 15;
    int wv   = idx >> 12;                          // 0..7
    int col = wv * 64 + n * 16 + (lane & 15);
    int k0  = kc * 32 + (lane >> 4) * 8;
    short8 v;
#pragma unroll
    for (int j = 0; j < 8; ++j) v[j] = (short)f2bf(W[(size_t)col * DH + k0 + j]);
    *reinterpret_cast<short8*>(Wp + (size_t)idx * 8) = v;
}

// ---------------------------------------------------------------------------
// Phase 1: xp = x @ W_ih^T + b_ih + b_hh, bf16, written in xpidx layout.
// M=262144, N=512, K=256.  Tile: 128(M) x 256(N), BK=64, 8 waves.
// ---------------------------------------------------------------------------
__global__ __launch_bounds__(512) void xproj_kernel(
    const float* __restrict__ x, const float* __restrict__ W_ih,
    const float* __restrict__ b_ih, const float* __restrict__ b_hh,
    u16* __restrict__ xp) {
    __shared__ u16 As[128 * 64];
    __shared__ u16 Bs[256 * 64];
    const int tid  = threadIdx.x;
    const int lane = tid & 63;
    const int wid  = tid >> 6;     // 0..7
    const int wm   = wid >> 2;     // 0..1
    const int wn   = wid & 3;      // 0..3
    const int mt   = blockIdx.x;   // 0..2047
    const int nt   = blockIdx.y;   // 0..1

    f32x4 acc[4][4];
#pragma unroll
    for (int i = 0; i < 4; ++i)
#pragma unroll
        for (int j = 0; j < 4; ++j) acc[i][j] = (f32x4){0.f, 0.f, 0.f, 0.f};

    for (int kk = 0; kk < DIN; kk += 64) {
        __syncthreads();
        {   // stage A: 128 rows x 64 k (fp32 -> bf16), 16 elems/thread
            int r = tid >> 2, q = tid & 3;
            const float4* gp = (const float4*)(x + (size_t)(mt * 128 + r) * DIN + kk + q * 16);
            float4 v0 = gp[0], v1 = gp[1], v2 = gp[2], v3 = gp[3];
            short8 h0, h1;
            h0[0]=(short)f2bf(v0.x); h0[1]=(short)f2bf(v0.y); h0[2]=(short)f2bf(v0.z); h0[3]=(short)f2bf(v0.w);
            h0[4]=(short)f2bf(v1.x); h0[5]=(short)f2bf(v1.y); h0[6]=(short)f2bf(v1.z); h0[7]=(short)f2bf(v1.w);
            h1[0]=(short)f2bf(v2.x); h1[1]=(short)f2bf(v2.y); h1[2]=(short)f2bf(v2.z); h1[3]=(short)f2bf(v2.w);
            h1[4]=(short)f2bf(v3.x); h1[5]=(short)f2bf(v3.y); h1[6]=(short)f2bf(v3.z); h1[7]=(short)f2bf(v3.w);
            int base = r * 64, sw = (r & 7) << 3, ke = q * 16;
            *(short8*)&As[base + (ke ^ sw)]       = h0;
            *(short8*)&As[base + ((ke + 8) ^ sw)] = h1;
        }
        {   // stage B: 256 rows x 64 k, 32 elems/thread
            int r = tid >> 1, hf = tid & 1;
            const float4* gp = (const float4*)(W_ih + (size_t)(nt * 256 + r) * DIN + kk + hf * 32);
            int base = r * 64, sw = (r & 7) << 3;
#pragma unroll
            for (int cp = 0; cp < 2; ++cp) {
                float4 u0 = gp[cp*4+0], u1 = gp[cp*4+1], u2 = gp[cp*4+2], u3 = gp[cp*4+3];
                short8 t0, t1;
                t0[0]=(short)f2bf(u0.x); t0[1]=(short)f2bf(u0.y); t0[2]=(short)f2bf(u0.z); t0[3]=(short)f2bf(u0.w);
                t0[4]=(short)f2bf(u1.x); t0[5]=(short)f2bf(u1.y); t0[6]=(short)f2bf(u1.z); t0[7]=(short)f2bf(u1.w);
                t1[0]=(short)f2bf(u2.x); t1[1]=(short)f2bf(u2.y); t1[2]=(short)f2bf(u2.z); t1[3]=(short)f2bf(u2.w);
                t1[4]=(short)f2bf(u3.x); t1[5]=(short)f2bf(u3.y); t1[6]=(short)f2bf(u3.z); t1[7]=(short)f2bf(u3.w);
                int ke = hf * 32 + cp * 16;
                *(short8*)&Bs[base + (ke ^ sw)]       = t0;
                *(short8*)&Bs[base + ((ke + 8) ^ sw)] = t1;
            }
        }
        __syncthreads();
#pragma unroll
        for (int kt = 0; kt < 2; ++kt) {
            short8 a[4], b[4];
            int ke = kt * 32 + (lane >> 4) * 8;
#pragma unroll
            for (int mi = 0; mi < 4; ++mi) {
                int rr = wm * 64 + mi * 16 + (lane & 15);
                a[mi] = *(const short8*)&As[rr * 64 + (ke ^ ((rr & 7) << 3))];
            }
#pragma unroll
            for (int ni = 0; ni < 4; ++ni) {
                int rr = wn * 64 + ni * 16 + (lane & 15);
                b[ni] = *(const short8*)&Bs[rr * 64 + (ke ^ ((rr & 7) << 3))];
            }
#pragma unroll
            for (int mi = 0; mi < 4; ++mi)
#pragma unroll
                for (int ni = 0; ni < 4; ++ni)
                    acc[mi][ni] = __builtin_amdgcn_mfma_f32_16x16x32_bf16(a[mi], b[ni], acc[mi][ni], 0, 0, 0);
        }
    }
    // epilogue -> xpidx layout. t = mt, bblk = wm*4+mi, wv = nt*4+wn, n = ni.
    int g4 = lane >> 4, c = lane & 15;
#pragma unroll
    for (int ni = 0; ni < 4; ++ni) {
        int col = nt * 256 + wn * 64 + ni * 16 + c;
        float bias = b_ih[col] + b_hh[col];
#pragma unroll
        for (int mi = 0; mi < 4; ++mi) {
            u32 lo = (u32)f2bf(acc[mi][ni][0] + bias) | ((u32)f2bf(acc[mi][ni][1] + bias) << 16);
            u32 hi = (u32)f2bf(acc[mi][ni][2] + bias) | ((u32)f2bf(acc[mi][ni][3] + bias) << 16);
            uint2 v; v.x = lo; v.y = hi;
            *reinterpret_cast<uint2*>(xp + xpidx(mt, wm * 4 + mi, nt * 4 + wn, ni, g4, c)) = v;
        }
    }
}

// ---------------------------------------------------------------------------
// Phase 2: recurrence. 8 blocks x 512 thr (8 waves, 2/SIMD), 1 block/CU.
// KEY FIX (r7 post-mortem): __launch_bounds__'s 2nd arg is only a MIN
// waves/EU — the compiler still targets HIGHER occupancy and remats W to
// fit 128 regs (r2/r6/r7 all allocated for the next occupancy bin).
// amdgpu_waves_per_eu(2,2) pins max=min=2 -> 256-reg budget, occupancy
// heuristic disabled -> the 160-reg W array can stay resident.
// Wave wv owns H-cols [64wv, 64wv+64), 4 n-frags. W_hh split:
//   kc 0..9   -> registers (40 frags = 160 regs; demand ~235 < 256)
//   kc 10..12 -> LDS (96 KB, DS pipe)
//   kc 13..15 -> streamed from L2 each step (96 KB/CU, VMEM pipe; stream
//                pointer re-defined per-iter by empty asm so LICM can't
//                hoist 48 regs of loads — correctness-proven in r3)
// h double-buffered in 32 KB LDS (total 128 KB). acc initialized from xp.
// All MFMAs are intrinsics (compiler owns all hazards — r4/r5 lesson).
// ---------------------------------------------------------------------------
__global__ __launch_bounds__(512)
__attribute__((amdgpu_waves_per_eu(2, 2)))
void rnn_rec_kernel(
    const u16* __restrict__ xp, const u16* __restrict__ Wp,
    u16* __restrict__ h_last) {
    __shared__ u16 W_lds[8 * 3 * 4 * 512];   // 96 KB : kc 10..12
    __shared__ u16 h_s[2][16 * 512];         // 32 KB
    const int tid = threadIdx.x, lane = tid & 63, wv = tid >> 6;  // wv 0..7
    const int bb = blockIdx.x;
    const int g4 = lane >> 4, c = lane & 15;
    const int arow = lane & 15;
    const int asw = (arow & 7) << 3;

    // stage W kc=10..12 into LDS (each wave its own 12 KB slice)
#pragma unroll
    for (int f = 0; f < 12; ++f) {           // f = q*4 + n, q = kc-10
        int q = f >> 2, n = f & 3;
        short8 v = *(const short8*)(Wp + ((size_t)((wv * 16 + 10 + q) * 4 + n)) * 512 + lane * 8);
        *(short8*)&W_lds[((wv * 3 + q) * 4 + n) * 512 + lane * 8] = v;
    }
    // W kc=0..9 into registers (40 x short8 = 160 regs). Budget is now a
    // real 256 (waves_per_eu(2,2)); demand ~235 -> no remat incentive.
    short8 wr[10][4];
#pragma unroll
    for (int kc = 0; kc < 10; ++kc)
#pragma unroll
        for (int n = 0; n < 4; ++n)
            wr[kc][n] = *(const short8*)(Wp + ((size_t)((wv * 16 + kc) * 4 + n)) * 512 + lane * 8);

    // h(0) = 0
    *(short8*)&h_s[0][tid * 16]     = (short8)0;
    *(short8*)&h_s[0][tid * 16 + 8] = (short8)0;

    // prefetch xp(0)
    uint2 xn[4];
#pragma unroll
    for (int n = 0; n < 4; ++n)
        xn[n] = *(const uint2*)(xp + xpidx(0, bb, wv, n, g4, c));

    const u16* wps_base = Wp + ((size_t)(wv * 16 + 13) * 4) * 512 + lane * 8;

    __syncthreads();

    for (int t = 0; t < SEQ; ++t) {
        const int cur = t & 1, nxt = cur ^ 1;

        // break loop-invariance of the streamed-W address each iteration
        const u16* wps = wps_base;
        asm volatile("" : "+v"(wps));

        // acc initialized from xp(t) (held in xn) — VALU; intrinsic MFMAs
        // follow, so the compiler owns the VALU->MFMA hazard.
        f32x4 acc[4];
#pragma unroll
        for (int n = 0; n < 4; ++n) {
            acc[n][0] = __uint_as_float(xn[n].x << 16);
            acc[n][1] = __uint_as_float(xn[n].x & 0xffff0000u);
            acc[n][2] = __uint_as_float(xn[n].y << 16);
            acc[n][3] = __uint_as_float(xn[n].y & 0xffff0000u);
        }
        // prefetch xp(t+1)
        if (t + 1 < SEQ) {
#pragma unroll
            for (int n = 0; n < 4; ++n)
                xn[n] = *(const uint2*)(xp + xpidx(t + 1, bb, wv, n, g4, c));
        }

        // kc 0..9 : B from registers
#pragma unroll
        for (int kc = 0; kc < 10; ++kc) {
            short8 a = *(const short8*)&h_s[cur][arow * 512 + ((kc * 32 + g4 * 8) ^ asw)];
#pragma unroll
            for (int n = 0; n < 4; ++n)
                acc[n] = __builtin_amdgcn_mfma_f32_16x16x32_bf16(a, wr[kc][n], acc[n], 0, 0, 0);
        }
        // kc 10..12 : B from LDS (DS pipe)
#pragma unroll
        for (int q = 0; q < 3; ++q) {
            int kc = 10 + q;
            short8 a = *(const short8*)&h_s[cur][arow * 512 + ((kc * 32 + g4 * 8) ^ asw)];
#pragma unroll
            for (int n = 0; n < 4; ++n) {
                short8 b = *(const short8*)&W_lds[((wv * 3 + q) * 4 + n) * 512 + lane * 8];
                acc[n] = __builtin_amdgcn_mfma_f32_16x16x32_bf16(a, b, acc[n], 0, 0, 0);
            }
        }
        // kc 13..15 : B streamed from L2 (VMEM pipe)
#pragma unroll
        for (int s = 0; s < 3; ++s) {
            int kc = 13 + s;
            short8 a = *(const short8*)&h_s[cur][arow * 512 + ((kc * 32 + g4 * 8) ^ asw)];
#pragma unroll
            for (int n = 0; n < 4; ++n) {
                short8 b = *(const short8*)(wps + (size_t)(s * 4 + n) * 512);
                acc[n] = __builtin_amdgcn_mfma_f32_16x16x32_bf16(a, b, acc[n], 0, 0, 0);
            }
        }

        // epilogue: acc row r -> batch row 4*g4+r, col = wv*64 + n*16 + c
#pragma unroll
        for (int n = 0; n < 4; ++n) {
            int colL = wv * 64 + n * 16 + c;
#pragma unroll
            for (int r = 0; r < 4; ++r) {
                int row = 4 * g4 + r;
                h_s[nxt][row * 512 + (colL ^ ((row & 7) << 3))] = f2bf(tanh_fast(acc[n][r]));
            }
        }
        __syncthreads();
    }
    {   // final h is in h_s[0] (SEQ even). Un-swizzle and store 16 u16/thread.
        int i = tid * 16;
        int row = i >> 9, colb = i & 511;
        int sw = (row & 7) << 3;
        short8 v0 = *(const short8*)&h_s[0][row * 512 + (colb ^ sw)];
        short8 v1 = *(const short8*)&h_s[0][row * 512 + ((colb + 8) ^ sw)];
        *(short8*)(h_last + (size_t)(bb * 16 + row) * DH + colb)     = v0;
        *(short8*)(h_last + (size_t)(bb * 16 + row) * DH + colb + 8) = v1;
    }
}

// ---------------------------------------------------------------------------
// Phase 3: out[b][o] = h_last[b,:]·W_fc[o,:] + b_fc[o]   (fp32 VALU, tiny)
// ---------------------------------------------------------------------------
__global__ __launch_bounds__(256) void fc_kernel(
    const u16* __restrict__ h_last, const float* __restrict__ W_fc,
    const float* __restrict__ b_fc, float* __restrict__ out) {
    __shared__ float hsh[DH];
    int b = blockIdx.x, o = threadIdx.x;
    for (int i = threadIdx.x; i < DH; i += 256) hsh[i] = bf2f(h_last[(size_t)b * DH + i]);
    __syncthreads();
    const float* w = W_fc + (size_t)o * DH;
    float s = 0.f;
#pragma unroll 8
    for (int k = 0; k < DH; ++k) s += hsh[k] * w[k];
    out[(size_t)b * DOUT + o] = s + b_fc[o];
}

extern "C" void kernel_launch(void* const* d_in, const int* in_sizes, int n_in,
                              void* d_out, int out_size, void* d_ws, size_t ws_size,
                              hipStream_t stream) {
    const float* x    = (const float*)d_in[0];
    const float* W_ih = (const float*)d_in[1];
    const float* W_hh = (const float*)d_in[2];
    const float* b_ih = (const float*)d_in[3];
    const float* b_hh = (const float*)d_in[4];
    const float* W_fc = (const float*)d_in[5];
    const float* b_fc = (const float*)d_in[6];
    float* out = (float*)d_out;

    u16* xp     = (u16*)d_ws;                               // 2048*128*512 bf16 = 256 MB
    u16* Wp     = xp + (size_t)SEQ * BATCH * DH;            // 512 KB
    u16* h_last = Wp + (size_t)8 * 16 * 4 * 512;            // 128 KB

    hipLaunchKernelGGL(pack_whh_kernel, dim3(128), dim3(256), 0, stream, W_hh, Wp);
    hipLaunchKernelGGL(xproj_kernel, dim3(2048, 2), dim3(512), 0, stream, x, W_ih, b_ih, b_hh, xp);
    hipLaunchKernelGGL(rnn_rec_kernel, dim3(8), dim3(512), 0, stream, xp, Wp, h_last);
    hipLaunchKernelGGL(fc_kernel, dim3(128), dim3(256), 0, stream, h_last, W_fc, b_fc, out);
}